// Round 9
// baseline (64.935 us; speedup 1.0000x reference)
//
#include <hip/hip_runtime.h>
#include <hip/hip_bf16.h>
#include <math.h>

// B=64, C=271, S=512, O=512, K=32.
// out[b,p,q] = sum_c pw[p,c]*y[b,c,q] + pb[p],  y[b,c,q] = sum_s x[b,c,s]*att[s,q]
// att = softmax_o( GT[128,o] . u[c,128] )  (separable fourier reduction)
// gemm7: A=xb[17408p][512] bf16, BT=attT[384p][512] -> yT[(b*271+q)][288p] bf16
// gemm8: A=pwb[512][288] bf16, BT=yT[17408][288] -> out[b,p,q] f32 + bias
// GEMM: 128x128 tile, 4 waves of 64x64 (acc 4x4, m97-verified geometry),
// 3-buffer LDS pipeline w/ counted vmcnt (4 load events/K-step -> vmcnt(4)),
// XOR swizzle both-sides (rule 21), LDS-transpose epilogue for yT stores.

typedef short s16x8 __attribute__((ext_vector_type(8)));
typedef short s16x4 __attribute__((ext_vector_type(4)));
typedef float f32x4 __attribute__((ext_vector_type(4)));

#define GLOBAL_AS __attribute__((address_space(1)))
#define LDS_AS    __attribute__((address_space(3)))

__device__ __forceinline__ short f2bf(float f) {
    __hip_bfloat16 h = __float2bfloat16(f);
    return *reinterpret_cast<short*>(&h);
}

#define Cdim 271
#define CpK  288
#define Sdim 512
#define Odim 512
#define MF   17344
#define MFp  17408

// 128x128 tile, 256 threads = 4 waves (2m x 2n), per-wave 64x64, nk >= 3.
// SWAP: if 1, blockIdx.x is the row tile (m), y the col tile (n).
template<int MODE, int SWAP>
__global__ __launch_bounds__(256, 3) void gemm_bf16(
    const short* __restrict__ A, int lda,
    const short* __restrict__ BT, int ldb,
    int nk,
    void* __restrict__ OutV,
    const float* __restrict__ bias)
{
    const int m0 = (SWAP ? blockIdx.x : blockIdx.y) * 128;
    const int n0 = (SWAP ? blockIdx.y : blockIdx.x) * 128;

    // 48KB pool: A bufs @ buf*4096, B bufs @ 12288 + buf*4096 (shorts).
    // MODE0 epilogue reuses pool[0..16896) as the 128x132 transpose tile.
    __shared__ short pool[24576];

    const int t = threadIdx.x;
    const int lane = t & 63;
    const int wid = t >> 6;            // 0..3
    const int wr = wid >> 1;           // 0..1 : m-offset wr*64
    const int wc = wid & 1;            // 0..1 : n-offset wc*64
    const int lr = lane & 15, lkq = lane >> 4;

    f32x4 acc[4][4];
    #pragma unroll
    for (int i = 0; i < 4; ++i)
        #pragma unroll
        for (int j = 0; j < 4; ++j)
            acc[i][j] = (f32x4){0.f, 0.f, 0.f, 0.f};

    // staging: each thread loads 2 16B chunks per operand per K-step.
    // chunk c = t + i*256: row = c>>2 (0..127), slot = (c&3)^((c>>3)&3) (pre-swizzled).
    const int srow = t >> 2;                               // 0..63 (+64 for i=1)
    const int skk  = (((lane & 3) ^ ((lane >> 3) & 3)) * 8);
    const short* pA = A + (long)(m0 + srow) * lda + skk;
    const short* pB = BT + (long)(n0 + srow) * ldb + skk;
    const long a64 = 64L * lda;
    const long b64 = 64L * ldb;
    const int ldsOff = wid * 512;      // shorts (lane*16B implicit)

    // read offsets (shorts): row*32 + ((lkq ^ ((lr>>1)&3))<<3)
    const int kxs = ((lkq ^ ((lr >> 1) & 3)) << 3);
    const int aBase = (wr * 64 + lr) * 32 + kxs;
    const int bBase = (wc * 64 + lr) * 32 + kxs;

    auto stage = [&](int buf, int kt) {
        const int k0 = kt * 32;
        __builtin_amdgcn_global_load_lds((const GLOBAL_AS void*)(pA + k0),
            (LDS_AS void*)&pool[buf * 4096 + ldsOff], 16, 0, 0);
        __builtin_amdgcn_global_load_lds((const GLOBAL_AS void*)(pA + a64 + k0),
            (LDS_AS void*)&pool[buf * 4096 + 2048 + ldsOff], 16, 0, 0);
        __builtin_amdgcn_global_load_lds((const GLOBAL_AS void*)(pB + k0),
            (LDS_AS void*)&pool[12288 + buf * 4096 + ldsOff], 16, 0, 0);
        __builtin_amdgcn_global_load_lds((const GLOBAL_AS void*)(pB + b64 + k0),
            (LDS_AS void*)&pool[12288 + buf * 4096 + 2048 + ldsOff], 16, 0, 0);
    };

    auto compute = [&](int buf) {
        s16x8 af[4], bfv[4];
        #pragma unroll
        for (int m = 0; m < 4; ++m)
            af[m] = *(const s16x8*)&pool[buf * 4096 + aBase + m * 512];
        #pragma unroll
        for (int n = 0; n < 4; ++n)
            bfv[n] = *(const s16x8*)&pool[12288 + buf * 4096 + bBase + n * 512];
        #pragma unroll
        for (int m = 0; m < 4; ++m)
            #pragma unroll
            for (int n = 0; n < 4; ++n)
                acc[m][n] = __builtin_amdgcn_mfma_f32_16x16x32_bf16(af[m], bfv[n], acc[m][n], 0, 0, 0);
    };

    // prologue: 2 tiles in flight; steady-state stage(kt+2) after barrier(kt).
    stage(0, 0); stage(1, 1);
    int bc = 0, bs = 2;
    for (int kt = 0; kt < nk; ++kt) {
        if (kt + 1 < nk) asm volatile("s_waitcnt vmcnt(4)" ::: "memory");
        else             asm volatile("s_waitcnt vmcnt(0)" ::: "memory");
        __builtin_amdgcn_s_barrier();
        __builtin_amdgcn_sched_barrier(0);
        if (kt + 2 < nk) stage(bs, kt + 2);
        compute(bc);
        bc = (bc == 2) ? 0 : bc + 1;
        bs = (bs == 2) ? 0 : bs + 1;
    }

    if (MODE == 0) {
        // ---- LDS-transpose epilogue: T[q_local][m_local], stride 132 shorts.
        __syncthreads();   // all staging/reads done; pool reusable
        short* T = pool;
        #pragma unroll
        for (int i = 0; i < 4; ++i) {
            const int ml = wr * 64 + i * 16 + lkq * 4;
            #pragma unroll
            for (int j = 0; j < 4; ++j) {
                const int ql = wc * 64 + j * 16 + lr;
                s16x4 v;
                #pragma unroll
                for (int r = 0; r < 4; ++r) v[r] = f2bf(acc[i][j][r]);
                *(s16x4*)&T[ql * 132 + ml] = v;
            }
        }
        __syncthreads();
        // gather rows of T (contiguous m) -> contiguous yT stores
        short* Oy = (short*)OutV;
        #pragma unroll
        for (int p = 0; p < 8; ++p) {
            const int ql = p * 16 + (t >> 4);
            const int gq = n0 + ql;
            const int mlc = (t & 15) * 8;
            const s16x8 v = *(const s16x8*)&T[ql * 132 + mlc];
            const int gm0 = m0 + mlc;
            if (gq < Cdim && gm0 < MF) {
                const int b0 = gm0 / Cdim;
                const int c0 = gm0 - b0 * Cdim;
                if (c0 + 8 <= Cdim) {
                    *(s16x8*)&Oy[((long)b0 * Cdim + gq) * CpK + c0] = v;
                } else {
                    #pragma unroll
                    for (int r = 0; r < 8; ++r) {
                        const int gm = gm0 + r;
                        if (gm < MF) {
                            const int bb = gm / Cdim;
                            const int cc = gm - bb * Cdim;
                            Oy[((long)bb * Cdim + gq) * CpK + cc] = v[r];
                        }
                    }
                }
            }
        }
    } else {
        float* O = (float*)OutV;
        #pragma unroll
        for (int j = 0; j < 4; ++j) {
            const int gn = n0 + wc * 64 + j * 16 + lr;
            if (gn >= MF) continue;
            const int b = gn / Cdim;
            const int q = gn - b * Cdim;
            float* ob = O + (long)b * Odim * Cdim + q;
            #pragma unroll
            for (int i = 0; i < 4; ++i) {
                const int gmb = m0 + wr * 64 + i * 16 + lkq * 4;
                #pragma unroll
                for (int r = 0; r < 4; ++r) {
                    const int gm = gmb + r;
                    ob[(long)gm * Cdim] = acc[i][j][r] + bias[gm];
                }
            }
        }
    }
}

// ---------------- fused prep: conv_x | conv_pw | reduce_ff ----------------
#define CONVX_BLOCKS 4352   // 17408*512/8/256
#define PW_BLOCKS    576    // 512*288/256
#define FF_BLOCKS    256    // 2 'o' per block

__global__ __launch_bounds__(256) void prep(
    const float* __restrict__ x,  short* __restrict__ xb,
    const float* __restrict__ pw, short* __restrict__ pwb,
    const float* __restrict__ ff, float* __restrict__ GT)
{
    const int blk = blockIdx.x;
    const int t = threadIdx.x;

    if (blk < CONVX_BLOCKS) {
        const long i8 = ((long)blk * 256 + t) * 8;
        s16x8 v = {0, 0, 0, 0, 0, 0, 0, 0};
        if (i8 < (long)MF * Sdim) {
            const f32x4 u0 = *(const f32x4*)&x[i8];
            const f32x4 u1 = *(const f32x4*)&x[i8 + 4];
            #pragma unroll
            for (int j = 0; j < 4; ++j) { v[j] = f2bf(u0[j]); v[4 + j] = f2bf(u1[j]); }
        }
        *(s16x8*)&xb[i8] = v;
        return;
    }
    if (blk < CONVX_BLOCKS + PW_BLOCKS) {
        const int idx = (blk - CONVX_BLOCKS) * 256 + t;
        const int p = idx / CpK;
        const int k = idx - p * CpK;
        pwb[idx] = (k < Cdim) ? f2bf(pw[(long)p * Cdim + k]) : (short)0;
        return;
    }
    __shared__ float L[2][32 * 132];
    const int fb = blk - (CONVX_BLOCKS + PW_BLOCKS);
    const int half = t >> 7;
    const int tl = t & 127;
    const int o = fb * 2 + half;
    const float* base = ff + (long)o * 4096;
    #pragma unroll
    for (int ch = 0; ch < 8; ++ch) {
        const int g = ch * 512 + tl * 4;
        const f32x4 v = *(const f32x4*)&base[g];
        *(f32x4*)&L[half][(g >> 7) * 132 + (g & 127)] = v;
    }
    __syncthreads();
    const int gq = tl >> 5, idx = tl & 31;
    float s = 0.f;
    if (gq == 0 || gq == 2) {
        const int w = (gq == 0) ? 0 : 2;
        #pragma unroll 8
        for (int j = 0; j < 32; ++j) s += L[half][idx * 132 + j * 4 + w];
    } else {
        const int w = (gq == 1) ? 1 : 3;
        #pragma unroll 8
        for (int i = 0; i < 32; ++i) s += L[half][i * 132 + idx * 4 + w];
    }
    GT[tl * 512 + o] = s;
}

__device__ __forceinline__ float wave_max(float v) {
    #pragma unroll
    for (int off = 32; off; off >>= 1) v = fmaxf(v, __shfl_xor(v, off));
    return v;
}
__device__ __forceinline__ float wave_sum(float v) {
    #pragma unroll
    for (int off = 32; off; off >>= 1) v += __shfl_xor(v, off);
    return v;
}

// Fused: basis + logits (coalesced GT reads) + softmax over o + bf16 store.
__global__ __launch_bounds__(256) void att_fused(
    const float* __restrict__ GT,   // [128][512]
    const float* __restrict__ sp,   // [271][2]
    short* __restrict__ attT)       // [384][512]
{
    const int c = blockIdx.x;
    const int t = threadIdx.x;      // 0..255
    short* row = attT + (long)c * Sdim;
    if (c >= Cdim) {
        row[t] = 0; row[t + 256] = 0;
        return;
    }
    __shared__ float u[128];
    __shared__ float red[4];
    if (t < 128) {
        const int g = t >> 5, k = t & 31;
        const float f = 6.283185307179586477f * (float)k / 32.0f;
        const float p = sp[c * 2 + (g & 1)];
        const float ang = p * f;
        u[t] = (g < 2) ? sinf(ang) : cosf(ang);
    }
    __syncthreads();

    float l0 = 0.f, l1 = 0.f;
    #pragma unroll 8
    for (int k = 0; k < 128; ++k) {
        const float uk = u[k];
        l0 = fmaf(GT[k * 512 + t], uk, l0);
        l1 = fmaf(GT[k * 512 + t + 256], uk, l1);
    }

    const int lane = t & 63, wid = t >> 6;
    float m = wave_max(fmaxf(l0, l1));
    if (lane == 0) red[wid] = m;
    __syncthreads();
    m = fmaxf(fmaxf(red[0], red[1]), fmaxf(red[2], red[3]));
    const float e0 = expf(l0 - m), e1 = expf(l1 - m);
    float s = wave_sum(e0 + e1);
    __syncthreads();
    if (lane == 0) red[wid] = s;
    __syncthreads();
    s = red[0] + red[1] + red[2] + red[3];
    const float inv = 1.f / s;
    row[t]       = f2bf(e0 * inv);
    row[t + 256] = f2bf(e1 * inv);
}

extern "C" void kernel_launch(void* const* d_in, const int* in_sizes, int n_in,
                              void* d_out, int out_size, void* d_ws, size_t ws_size,
                              hipStream_t stream)
{
    const float* x  = (const float*)d_in[0];  // [B,C,S] = [17344][512]
    const float* ff = (const float*)d_in[1];  // [512,32,32,4]
    const float* sp = (const float*)d_in[2];  // [271,2]
    const float* pw = (const float*)d_in[3];  // [512,271]
    const float* pb = (const float*)d_in[4];  // [512]
    float* out = (float*)d_out;               // [64,512,271]

    const int S = Sdim, O = Odim;

    float* ws   = (float*)d_ws;
    float* GT   = ws;                           // 128*512 f32
    short* xb   = (short*)(GT + 128 * 512);     // 17408*512 bf16
    short* attT = xb + (long)MFp * S;           // 384*512 bf16
    short* pwb  = attT + 384L * S;              // 512*288 bf16
    short* yT   = pwb + (long)O * CpK;          // 17408*288 bf16

    // fused prep: x->bf16, pw->bf16 (padded), ff separable reduce -> GT
    prep<<<CONVX_BLOCKS + PW_BLOCKS + FF_BLOCKS, 256, 0, stream>>>(
        x, xb, pw, pwb, ff, GT);

    // basis + logits + softmax + bf16 transpose-store
    att_fused<<<384, 256, 0, stream>>>(GT, sp, attT);

    // gemm7: yT[(b*271+q)][c] = sum_s xb[(b,c)][s] * attT[q][s]
    // grid row-fastest: 3 sharers of each A-row-tile spaced 136 = 0 mod 8.
    gemm_bf16<0, 1><<<dim3(MFp / 128, 3), 256, 0, stream>>>(
        xb, S, attT, S, S / 32, (void*)yT, nullptr);

    // gemm8: out[b,p,q] = sum_k pwb[p][k] * yT[(b*271+q)][k] + pb[p]
    // grid col-fastest: 4 sharers of each yT row-tile spaced 136 = 0 mod 8.
    gemm_bf16<1, 0><<<dim3(MFp / 128, O / 128), 256, 0, stream>>>(
        pwb, CpK, yT, CpK, CpK / 32, (void*)out, pb);
}

// Round 10
// 57.951 us; speedup vs baseline: 1.1205x; 1.1205x over previous
//
#include <hip/hip_runtime.h>
#include <hip/hip_bf16.h>
#include <math.h>

// B=64, C=271, S=512, O=512, K=32.
// out[b,p,q] = sum_c pw[p,c]*y[b,c,q] + pb[p],  y[b,c,q] = sum_s x[b,c,s]*att[s,q]
// att = softmax_o( GT[128,o] . u[c,128] )  (separable fourier reduction)
// gemm7: A = x (f32, staged reg->bf16->LDS, T14 split), BT=attT[384p][512]
//        -> yT[(b*271+q)][288p] bf16   (LDS-transpose epilogue)
// gemm8: A=pwb[512][288] bf16, BT=yT[17408][288] -> out f32 + bias (gload_lds)
// Schedule: 3-buffer LDS pipeline, counted vmcnt; 8 waves (R8-proven geometry).
// XOR swizzle both-sides (rule 21): phys slot s of row r holds chunk s^((r>>1)&3).

typedef short s16x8 __attribute__((ext_vector_type(8)));
typedef short s16x4 __attribute__((ext_vector_type(4)));
typedef float f32x4 __attribute__((ext_vector_type(4)));

#define GLOBAL_AS __attribute__((address_space(1)))
#define LDS_AS    __attribute__((address_space(3)))

__device__ __forceinline__ short f2bf(float f) {
    __hip_bfloat16 h = __float2bfloat16(f);
    return *reinterpret_cast<short*>(&h);
}

#define Cdim 271
#define CpK  288
#define Sdim 512
#define Odim 512
#define MF   17344
#define MFp  17408

// 128x128 tile, 512 threads = 8 waves (2m x 4n), per-wave 64x32, nk >= 3.
// SWAP: 1 -> blockIdx.x is the row tile. AF32: A operand is f32 (reg-staged).
template<int MODE, int SWAP, int AF32>
__global__ __launch_bounds__(512) void gemm_bf16(
    const void* __restrict__ Av, int lda,
    const short* __restrict__ BT, int ldb,
    int nk,
    void* __restrict__ OutV,
    const float* __restrict__ bias)
{
    const int m0 = (SWAP ? blockIdx.x : blockIdx.y) * 128;
    const int n0 = (SWAP ? blockIdx.y : blockIdx.x) * 128;

    // 48KB pool: A bufs @ buf*4096, B bufs @ 12288+buf*4096 (shorts).
    // MODE0 epilogue reuses pool[0..16896) as the 128x132 transpose tile.
    __shared__ short pool[24576];

    const int t = threadIdx.x;
    const int lane = t & 63;
    const int wid = t >> 6;            // 0..7
    const int wr = wid >> 2;           // 0..1 : m-offset wr*64
    const int wc = wid & 3;            // 0..3 : n-offset wc*32
    const int lr = lane & 15, lkq = lane >> 4;

    f32x4 acc[4][2];
    #pragma unroll
    for (int i = 0; i < 4; ++i)
        #pragma unroll
        for (int j = 0; j < 2; ++j)
            acc[i][j] = (f32x4){0.f, 0.f, 0.f, 0.f};

    // ---- B staging (gload_lds, bf16): linear LDS dest, pre-swizzled source.
    const int srowB = wid * 16 + (lane >> 2);
    const int skk   = (((lane & 3) ^ ((lane >> 3) & 3)) * 8);
    const short* pB = BT + (long)(n0 + srowB) * ldb + skk;
    const int ldsOff = wid * 512;      // shorts

    // ---- A staging
    // AF32=0: same gload_lds as B.
    // AF32=1: row = t>>2 (4 thr/row), slot = t&3, global chunk = slot^((row>>1)&3);
    //         load 8 f32, cvt, ds_write_b128 to row*32 + slot*8 (same phys layout).
    const short* pA_bf = (const short*)Av + (long)(m0 + srowB) * lda + skk;
    const int arow = t >> 2;
    const int aslot = t & 3;
    const int afc = (aslot ^ ((arow >> 1) & 3)) * 8;
    const int agrow = (m0 + arow < MF) ? (m0 + arow) : (MF - 1);  // clamp pad rows
    const float* pA_f32 = (const float*)Av + (long)agrow * lda + afc;
    const int aWr = arow * 32 + aslot * 8;   // LDS write offset (shorts)

    // read offsets (shorts): row*32 + ((lkq ^ ((lr>>1)&3))<<3)
    const int kxs = ((lkq ^ ((lr >> 1) & 3)) << 3);
    const int aBase = (wr * 64 + lr) * 32 + kxs;
    const int bBase = (wc * 32 + lr) * 32 + kxs;

    auto stageB = [&](int buf, int kt) {
        __builtin_amdgcn_global_load_lds((const GLOBAL_AS void*)(pB + kt * 32),
            (LDS_AS void*)&pool[12288 + buf * 4096 + ldsOff], 16, 0, 0);
    };
    auto stageA_bf = [&](int buf, int kt) {
        __builtin_amdgcn_global_load_lds((const GLOBAL_AS void*)(pA_bf + kt * 32),
            (LDS_AS void*)&pool[buf * 4096 + ldsOff], 16, 0, 0);
    };

    auto compute = [&](int buf) {
        s16x8 af[4], bfv[2];
        #pragma unroll
        for (int m = 0; m < 4; ++m)
            af[m] = *(const s16x8*)&pool[buf * 4096 + aBase + m * 512];
        #pragma unroll
        for (int n = 0; n < 2; ++n)
            bfv[n] = *(const s16x8*)&pool[12288 + buf * 4096 + bBase + n * 512];
        #pragma unroll
        for (int m = 0; m < 4; ++m)
            #pragma unroll
            for (int n = 0; n < 2; ++n)
                acc[m][n] = __builtin_amdgcn_mfma_f32_16x16x32_bf16(af[m], bfv[n], acc[m][n], 0, 0, 0);
    };

    if (AF32) {
        // -------- reg-staged A pipeline (T14 split: issue early, write late) ----
        f32x4 aP0, aP1, aN0, aN1;
        auto loadA = [&](int kt, f32x4& v0, f32x4& v1) {
            const float* p = pA_f32 + kt * 32;
            v0 = *(const f32x4 GLOBAL_AS*)(p);
            v1 = *(const f32x4 GLOBAL_AS*)(p + 4);
        };
        auto writeA = [&](int buf, const f32x4& v0, const f32x4& v1) {
            s16x8 w;
            #pragma unroll
            for (int j = 0; j < 4; ++j) { w[j] = f2bf(v0[j]); w[4 + j] = f2bf(v1[j]); }
            *(s16x8*)&pool[buf * 4096 + aWr] = w;   // compiler waits loads here
        };
        // prologue: tile0 written, tile1 loads in flight
        loadA(0, aP0, aP1); stageB(0, 0);
        writeA(0, aP0, aP1);
        loadA(1, aP0, aP1); stageB(1, 1);
        int bc = 0, bs = 2;
        for (int kt = 0; kt < nk; ++kt) {
            if (kt + 1 < nk) asm volatile("s_waitcnt vmcnt(3) lgkmcnt(0)" ::: "memory");
            else             asm volatile("s_waitcnt vmcnt(0) lgkmcnt(0)" ::: "memory");
            __builtin_amdgcn_s_barrier();
            __builtin_amdgcn_sched_barrier(0);
            if (kt + 2 < nk) { loadA(kt + 2, aN0, aN1); stageB(bs, kt + 2); }
            compute(bc);
            if (kt + 1 < nk) writeA((bc == 2) ? 0 : bc + 1, aP0, aP1);
            aP0 = aN0; aP1 = aN1;
            bc = (bc == 2) ? 0 : bc + 1;
            bs = (bs == 2) ? 0 : bs + 1;
        }
    } else {
        // -------- pure gload_lds pipeline (R8-proven) --------
        stageA_bf(0, 0); stageB(0, 0);
        stageA_bf(1, 1); stageB(1, 1);
        int bc = 0, bs = 2;
        for (int kt = 0; kt < nk; ++kt) {
            if (kt + 1 < nk) asm volatile("s_waitcnt vmcnt(2)" ::: "memory");
            else             asm volatile("s_waitcnt vmcnt(0)" ::: "memory");
            __builtin_amdgcn_s_barrier();
            __builtin_amdgcn_sched_barrier(0);
            if (kt + 2 < nk) { stageA_bf(bs, kt + 2); stageB(bs, kt + 2); }
            compute(bc);
            bc = (bc == 2) ? 0 : bc + 1;
            bs = (bs == 2) ? 0 : bs + 1;
        }
    }

    if (MODE == 0) {
        // ---- LDS-transpose epilogue: T[q_local][m_local], stride 132 shorts.
        __syncthreads();
        short* T = pool;
        #pragma unroll
        for (int i = 0; i < 4; ++i) {
            const int ml = wr * 64 + i * 16 + lkq * 4;
            #pragma unroll
            for (int j = 0; j < 2; ++j) {
                const int ql = wc * 32 + j * 16 + lr;
                s16x4 v;
                #pragma unroll
                for (int r = 0; r < 4; ++r) v[r] = f2bf(acc[i][j][r]);
                *(s16x4*)&T[ql * 132 + ml] = v;
            }
        }
        __syncthreads();
        short* Oy = (short*)OutV;
        #pragma unroll
        for (int p = 0; p < 4; ++p) {
            const int ql = p * 32 + (t >> 4);
            const int gq = n0 + ql;
            const int mlc = (t & 15) * 8;
            const s16x8 v = *(const s16x8*)&T[ql * 132 + mlc];
            const int gm0 = m0 + mlc;
            if (gq < Cdim && gm0 < MF) {
                const int b0 = gm0 / Cdim;
                const int c0 = gm0 - b0 * Cdim;
                if (c0 + 8 <= Cdim) {
                    *(s16x8*)&Oy[((long)b0 * Cdim + gq) * CpK + c0] = v;
                } else {
                    #pragma unroll
                    for (int r = 0; r < 8; ++r) {
                        const int gm = gm0 + r;
                        if (gm < MF) {
                            const int bb = gm / Cdim;
                            const int cc = gm - bb * Cdim;
                            Oy[((long)bb * Cdim + gq) * CpK + cc] = v[r];
                        }
                    }
                }
            }
        }
    } else {
        float* O = (float*)OutV;
        #pragma unroll
        for (int j = 0; j < 2; ++j) {
            const int gn = n0 + wc * 32 + j * 16 + lr;
            if (gn >= MF) continue;
            const int b = gn / Cdim;
            const int q = gn - b * Cdim;
            float* ob = O + (long)b * Odim * Cdim + q;
            #pragma unroll
            for (int i = 0; i < 4; ++i) {
                const int gmb = m0 + wr * 64 + i * 16 + lkq * 4;
                #pragma unroll
                for (int r = 0; r < 4; ++r) {
                    const int gm = gmb + r;
                    ob[(long)gm * Cdim] = acc[i][j][r] + bias[gm];
                }
            }
        }
    }
}

// ---------------- ff separable reduction -> GT[128][512] ----------------
__global__ __launch_bounds__(256) void ff_reduce(const float* __restrict__ ff,
                                                 float* __restrict__ GT)
{
    __shared__ float L[2][32 * 132];
    const int t = threadIdx.x;
    const int half = t >> 7;
    const int tl = t & 127;
    const int o = blockIdx.x * 2 + half;
    const float* base = ff + (long)o * 4096;
    #pragma unroll
    for (int ch = 0; ch < 8; ++ch) {
        const int g = ch * 512 + tl * 4;
        const f32x4 v = *(const f32x4*)&base[g];
        *(f32x4*)&L[half][(g >> 7) * 132 + (g & 127)] = v;
    }
    __syncthreads();
    const int gq = tl >> 5, idx = tl & 31;
    float s = 0.f;
    if (gq == 0 || gq == 2) {
        const int w = (gq == 0) ? 0 : 2;
        #pragma unroll 8
        for (int j = 0; j < 32; ++j) s += L[half][idx * 132 + j * 4 + w];
    } else {
        const int w = (gq == 1) ? 1 : 3;
        #pragma unroll 8
        for (int i = 0; i < 32; ++i) s += L[half][i * 132 + idx * 4 + w];
    }
    GT[tl * 512 + o] = s;
}

__device__ __forceinline__ float wave_max(float v) {
    #pragma unroll
    for (int off = 32; off; off >>= 1) v = fmaxf(v, __shfl_xor(v, off));
    return v;
}
__device__ __forceinline__ float wave_sum(float v) {
    #pragma unroll
    for (int off = 32; off; off >>= 1) v += __shfl_xor(v, off);
    return v;
}

// Fused: basis + logits + softmax + bf16 store. Pad-row blocks (c>=271)
// zero their attT row AND convert pw -> pwb (512x288, zero k-pad).
__global__ __launch_bounds__(256) void att_fused(
    const float* __restrict__ GT,   // [128][512]
    const float* __restrict__ sp,   // [271][2]
    short* __restrict__ attT,       // [384][512]
    const float* __restrict__ pw,   // [512][271]
    short* __restrict__ pwb)        // [512][288]
{
    const int c = blockIdx.x;
    const int t = threadIdx.x;      // 0..255
    short* row = attT + (long)c * Sdim;
    if (c >= Cdim) {
        row[t] = 0; row[t + 256] = 0;
        const int bi = c - Cdim;    // 0..112; first 72 blocks fill pwb
        if (bi < 72) {
            const int idx8 = (bi * 256 + t) * 8;   // < 147456 = 512*288
            const int p = idx8 / CpK;
            const int k0 = idx8 - p * CpK;
            s16x8 v;
            #pragma unroll
            for (int r = 0; r < 8; ++r) {
                const int k = k0 + r;
                v[r] = (k < Cdim) ? f2bf(pw[(long)p * Cdim + k]) : (short)0;
            }
            *(s16x8*)&pwb[idx8] = v;
        }
        return;
    }
    __shared__ float u[128];
    __shared__ float red[4];
    if (t < 128) {
        const int g = t >> 5, k = t & 31;
        const float f = 6.283185307179586477f * (float)k / 32.0f;
        const float p = sp[c * 2 + (g & 1)];
        const float ang = p * f;
        u[t] = (g < 2) ? sinf(ang) : cosf(ang);
    }
    __syncthreads();

    float l0 = 0.f, l1 = 0.f;
    #pragma unroll 8
    for (int k = 0; k < 128; ++k) {
        const float uk = u[k];
        l0 = fmaf(GT[k * 512 + t], uk, l0);
        l1 = fmaf(GT[k * 512 + t + 256], uk, l1);
    }

    const int lane = t & 63, wid = t >> 6;
    float m = wave_max(fmaxf(l0, l1));
    if (lane == 0) red[wid] = m;
    __syncthreads();
    m = fmaxf(fmaxf(red[0], red[1]), fmaxf(red[2], red[3]));
    const float e0 = expf(l0 - m), e1 = expf(l1 - m);
    float s = wave_sum(e0 + e1);
    __syncthreads();
    if (lane == 0) red[wid] = s;
    __syncthreads();
    s = red[0] + red[1] + red[2] + red[3];
    const float inv = 1.f / s;
    row[t]       = f2bf(e0 * inv);
    row[t + 256] = f2bf(e1 * inv);
}

extern "C" void kernel_launch(void* const* d_in, const int* in_sizes, int n_in,
                              void* d_out, int out_size, void* d_ws, size_t ws_size,
                              hipStream_t stream)
{
    const float* x  = (const float*)d_in[0];  // [B,C,S] = [17344][512]
    const float* ff = (const float*)d_in[1];  // [512,32,32,4]
    const float* sp = (const float*)d_in[2];  // [271,2]
    const float* pw = (const float*)d_in[3];  // [512,271]
    const float* pb = (const float*)d_in[4];  // [512]
    float* out = (float*)d_out;               // [64,512,271]

    const int S = Sdim, O = Odim;

    float* ws   = (float*)d_ws;
    float* GT   = ws;                           // 128*512 f32
    short* attT = (short*)(GT + 128 * 512);     // 384*512 bf16
    short* pwb  = attT + 384L * S;              // 512*288 bf16
    short* yT   = pwb + (long)O * CpK;          // 17408*288 bf16

    // ff separable reduce -> GT
    ff_reduce<<<256, 256, 0, stream>>>(ff, GT);

    // basis + logits + softmax + attT store; pad blocks also build pwb
    att_fused<<<384, 256, 0, stream>>>(GT, sp, attT, pw, pwb);

    // gemm7: yT[(b*271+q)][c] = sum_s x[(b,c)][s] * attT[q][s]  (A = f32 x)
    // grid row-fastest: 3 sharers of each A-row-tile spaced 136 = 0 mod 8.
    gemm_bf16<0, 1, 1><<<dim3(MFp / 128, 3), 512, 0, stream>>>(
        (const void*)x, S, attT, S, S / 32, (void*)yT, nullptr);

    // gemm8: out[b,p,q] = sum_k pwb[p][k] * yT[(b*271+q)][k] + pb[p]
    gemm_bf16<1, 0, 0><<<dim3(MFp / 128, O / 128), 512, 0, stream>>>(
        (const void*)pwb, CpK, yT, CpK, CpK / 32, (void*)out, pb);
}